// Round 5
// baseline (74.642 us; speedup 1.0000x reference)
//
#include <hip/hip_runtime.h>
#include <math.h>

#define RR 32
#define R3 (RR*RR*RR)
#define BATCH 8
#define NPTS 32768
#define CCH 64

static constexpr int DNB  = BATCH;            // denom blocks (one per batch)
static constexpr int VZB  = 1024;             // voxf zero blocks (64KB each)
static constexpr int CZB  = 16;               // counts zero blocks (64KB each)
static constexpr int WPB  = 512;              // feature waves per batch
static constexpr int PPW  = NPTS / WPB;       // points per wave (64)
static constexpr int FBLK = WPB / 4;          // feature blocks per batch (128)

// ---------------- K1: denom (blocks 0..7) + zero voxf/counts (blocks 8..) ----------------
__global__ __launch_bounds__(256) void prep_kernel(const float* __restrict__ coords,
                                                   float* __restrict__ voxf,
                                                   int* __restrict__ counts,
                                                   float* __restrict__ denom) {
    int bx = blockIdx.x;
    int tid = threadIdx.x;
    if (bx < DNB) {
        // per-batch sum of squares of mean-subtracted components (fp32)
        int b = bx;
        const float* cbase = coords + (size_t)b * NPTS * 3;
        float sx = 0.f, sy = 0.f, sz = 0.f;
        for (int n = tid; n < NPTS; n += 256) {
            const float* p = cbase + n * 3;
            float x = p[0], y = p[1], z = p[2];
            float m = (x + y + z) * (1.0f / 3.0f);
            float dx = x - m, dy = y - m, dz = z - m;
            sx += dx * dx; sy += dy * dy; sz += dz * dz;
        }
        #pragma unroll
        for (int off = 1; off < 64; off <<= 1) {
            sx += __shfl_xor(sx, off);
            sy += __shfl_xor(sy, off);
            sz += __shfl_xor(sz, off);
        }
        __shared__ float ls[3][4];
        int w = tid >> 6;
        if ((tid & 63) == 0) { ls[0][w] = sx; ls[1][w] = sy; ls[2][w] = sz; }
        __syncthreads();
        if (tid == 0) {
            float tx = ls[0][0] + ls[0][1] + ls[0][2] + ls[0][3];
            float ty = ls[1][0] + ls[1][1] + ls[1][2] + ls[1][3];
            float tz = ls[2][0] + ls[2][1] + ls[2][2] + ls[2][3];
            float mx = fmaxf(fmaxf(sqrtf(tx), sqrtf(ty)), sqrtf(tz));
            denom[b] = mx * 2.0f;
        }
        return;
    }
    int zb = bx - DNB;
    float4 z = make_float4(0.f, 0.f, 0.f, 0.f);
    if (zb < VZB) {
        float4* o4 = (float4*)voxf + (size_t)zb * 4096;
        #pragma unroll
        for (int k = 0; k < 16; ++k) o4[k * 256 + tid] = z;
    } else {
        float4* c4 = (float4*)counts + (size_t)(zb - VZB) * 4096;
        #pragma unroll
        for (int k = 0; k < 16; ++k) c4[k * 256 + tid] = z;
    }
}

// ---------------- K2: fused points+feat ----------------
// Per wave: 64 points. lane's own point -> coords/nc/voxel id; feature loads
// lane=(sub,cslice): sub=lane>>4 picks point subgroup, cb=(lane&15)*4 picks 4
// contiguous channels -> 16 float4 loads = the wave's full 16KB tile.
// Flush UNSCALED sums (no counts dependency); counts via aggregated atomics.
__global__ __launch_bounds__(256) void feat_kernel(const float* __restrict__ features,
                                                   const float* __restrict__ coords,
                                                   const float* __restrict__ denom,
                                                   float* __restrict__ nc_out,
                                                   int* __restrict__ counts,
                                                   float* __restrict__ out) {
    int b = blockIdx.y;
    int wave = (blockIdx.x * 256 + threadIdx.x) >> 6;
    int lane = threadIdx.x & 63;
    int sub = lane >> 4;
    int cb  = (lane & 15) << 2;
    const float* fbase = features + (size_t)b * NPTS * CCH;
    const float* crd = coords + (size_t)b * NPTS * 3;
    int* cnt = counts + (size_t)b * R3;
    float* obase = out + (size_t)b * CCH * R3;
    int p0 = wave * PPW;

    // issue the 16KB feature tile first (max loads in flight)
    float4 f[16];
    #pragma unroll
    for (int i = 0; i < 16; ++i)
        f[i] = *(const float4*)(fbase + (size_t)(p0 + i * 4 + sub) * CCH + cb);

    // this lane's own point: nc + voxel id
    int pp = p0 + lane;
    float x = crd[pp * 3], y = crd[pp * 3 + 1], zz = crd[pp * 3 + 2];
    float rd = 1.0f / denom[b];
    float m = (x + y + zz) * (1.0f / 3.0f);
    float fx = (x - m) * rd + 0.5f;
    float fy = (y - m) * rd + 0.5f;
    float fz = (zz - m) * rd + 0.5f;
    float tx = fminf(fmaxf(fx * (float)RR, 0.0f), (float)(RR - 1));
    float ty = fminf(fmaxf(fy * (float)RR, 0.0f), (float)(RR - 1));
    float tz = fminf(fmaxf(fz * (float)RR, 0.0f), (float)(RR - 1));
    float* onc = nc_out + (size_t)(b * NPTS + pp) * 3;
    onc[0] = tx; onc[1] = ty; onc[2] = tz;
    int v = (int)rintf(tx) * (RR * RR) + (int)rintf(ty) * RR + (int)rintf(tz);

    int v0 = __shfl(v, 0);
    bool uni = __all(v == v0);
    if (uni) {
        if (lane == 0) atomicAdd(&cnt[v0], 64);
        float4 s = f[0];
        #pragma unroll
        for (int i = 1; i < 16; ++i) {
            s.x += f[i].x; s.y += f[i].y; s.z += f[i].z; s.w += f[i].w;
        }
        s.x += __shfl_xor(s.x, 16); s.x += __shfl_xor(s.x, 32);
        s.y += __shfl_xor(s.y, 16); s.y += __shfl_xor(s.y, 32);
        s.z += __shfl_xor(s.z, 16); s.z += __shfl_xor(s.z, 32);
        s.w += __shfl_xor(s.w, 16); s.w += __shfl_xor(s.w, 32);
        if (sub == 0) {
            size_t o = (size_t)cb * R3 + v0;
            atomicAdd(&obase[o],          s.x);
            atomicAdd(&obase[o + R3],     s.y);
            atomicAdd(&obase[o + 2 * R3], s.z);
            atomicAdd(&obase[o + 3 * R3], s.w);
        }
    } else {
        atomicAdd(&cnt[v], 1);
        #pragma unroll
        for (int i = 0; i < 16; ++i) {
            int vv = __shfl(v, i * 4 + sub);
            size_t o = (size_t)cb * R3 + vv;
            atomicAdd(&obase[o],          f[i].x);
            atomicAdd(&obase[o + R3],     f[i].y);
            atomicAdd(&obase[o + 2 * R3], f[i].z);
            atomicAdd(&obase[o + 3 * R3], f[i].w);
        }
    }
}

// ---------------- K3: divide hot voxels by their counts ----------------
// One thread per (batch, voxel) scans counts; each voxel with cnt>1 is
// rescaled by the whole wave (lane = channel). cnt==0/1 need no scaling.
__global__ __launch_bounds__(256) void scale_kernel(const int* __restrict__ counts,
                                                    float* __restrict__ out) {
    int t = blockIdx.x * 256 + threadIdx.x;        // 0 .. B*R3-1
    int lane = threadIdx.x & 63;
    int b = t >> 15;                               // R3 = 32768
    int vox = t & (R3 - 1);
    int cnt = counts[t];
    unsigned long long mask = __ballot(cnt > 1);
    while (mask) {
        int src = __ffsll(mask) - 1;
        mask &= mask - 1;
        int vv = __shfl(vox, src);
        int bb = __shfl(b, src);
        int cc = __shfl(cnt, src);
        float s = 1.0f / (float)cc;
        size_t o = ((size_t)bb * CCH + lane) * R3 + vv;
        out[o] *= s;
    }
}

extern "C" void kernel_launch(void* const* d_in, const int* in_sizes, int n_in,
                              void* d_out, int out_size, void* d_ws, size_t ws_size,
                              hipStream_t stream) {
    const float* features = (const float*)d_in[0];
    const float* coords   = (const float*)d_in[1];
    float* out = (float*)d_out;

    float* voxf = out;                                    // (B, C, R, R, R)
    float* nc   = out + (size_t)BATCH * CCH * R3;         // (B, N, 3)

    char* ws = (char*)d_ws;
    int*   counts = (int*)ws;                             // B*R3 ints = 1 MiB
    float* denom  = (float*)(ws + (1 << 20));             // B floats

    prep_kernel<<<DNB + VZB + CZB, 256, 0, stream>>>(coords, voxf, counts, denom);

    dim3 fgrid(FBLK, BATCH);
    feat_kernel<<<fgrid, 256, 0, stream>>>(features, coords, denom, nc, counts, voxf);

    scale_kernel<<<BATCH * R3 / 256, 256, 0, stream>>>(counts, voxf);
}

// Round 6
// 41.678 us; speedup vs baseline: 1.7909x; 1.7909x over previous
//
#include <hip/hip_runtime.h>
#include <math.h>

#define RR 32
#define R3 (RR*RR*RR)
#define BATCH 8
#define NPTS 32768
#define CCH 64

static constexpr int SB   = 64;               // stats blocks per batch (slotted partials)
static constexpr int SBT  = SB * BATCH;       // 512 stats blocks total
static constexpr int VZB  = 1024;             // voxf zero blocks (64KB each)
static constexpr int CZB  = 16;               // counts zero blocks (64KB each)
static constexpr int WPB  = 512;              // feature waves per batch
static constexpr int PPW  = NPTS / WPB;       // points per wave (64)
static constexpr int FBLK = WPB / 4;          // feature blocks per batch (128)

// ---------------- K1: slotted stats partials + zero voxf/counts ----------------
// blocks [0, SBT): per-batch partial sum-of-squares, 512 points each (2 iters),
//                  each block writes its OWN slot -> no init, no atomics.
// blocks [SBT, SBT+VZB+CZB): zero voxf (64MB) and counts (1MB).
__global__ __launch_bounds__(256) void prep_kernel(const float* __restrict__ coords,
                                                   float* __restrict__ voxf,
                                                   int* __restrict__ counts,
                                                   float* __restrict__ partials) {
    int bx = blockIdx.x;
    int tid = threadIdx.x;
    if (bx < SBT) {
        int b = bx / SB;
        int sb = bx - b * SB;
        const float* cbase = coords + ((size_t)b * NPTS + sb * (NPTS / SB)) * 3;
        float sx = 0.f, sy = 0.f, sz = 0.f;
        #pragma unroll
        for (int k = 0; k < (NPTS / SB) / 256; ++k) {
            const float* p = cbase + (k * 256 + tid) * 3;
            float x = p[0], y = p[1], z = p[2];
            float m = (x + y + z) * (1.0f / 3.0f);
            float dx = x - m, dy = y - m, dz = z - m;
            sx += dx * dx; sy += dy * dy; sz += dz * dz;
        }
        #pragma unroll
        for (int off = 1; off < 64; off <<= 1) {
            sx += __shfl_xor(sx, off);
            sy += __shfl_xor(sy, off);
            sz += __shfl_xor(sz, off);
        }
        __shared__ float ls[3][4];
        int w = tid >> 6;
        if ((tid & 63) == 0) { ls[0][w] = sx; ls[1][w] = sy; ls[2][w] = sz; }
        __syncthreads();
        if (tid == 0) {
            float* o = partials + (size_t)bx * 3;
            o[0] = ls[0][0] + ls[0][1] + ls[0][2] + ls[0][3];
            o[1] = ls[1][0] + ls[1][1] + ls[1][2] + ls[1][3];
            o[2] = ls[2][0] + ls[2][1] + ls[2][2] + ls[2][3];
        }
        return;
    }
    int zb = bx - SBT;
    float4 z = make_float4(0.f, 0.f, 0.f, 0.f);
    if (zb < VZB) {
        float4* o4 = (float4*)voxf + (size_t)zb * 4096;
        #pragma unroll
        for (int k = 0; k < 16; ++k) o4[k * 256 + tid] = z;
    } else {
        float4* c4 = (float4*)counts + (size_t)(zb - VZB) * 4096;
        #pragma unroll
        for (int k = 0; k < 16; ++k) c4[k * 256 + tid] = z;
    }
}

// ---------------- K2: fused points+feat; denom re-reduced per wave ----------------
// Per wave: 64 points. Feature loads issued first (16 float4 = the wave's 16KB
// tile, lane=(sub,cslice)). Denom: lane=slot, 64 slots of 3 floats (L2-hot)
// + 6 shfl_xor -> every lane holds rd. Then own-point nc + voxel id, counts
// via aggregated atomic, UNSCALED feature sums flushed to out.
__global__ __launch_bounds__(256) void feat_kernel(const float* __restrict__ features,
                                                   const float* __restrict__ coords,
                                                   const float* __restrict__ partials,
                                                   float* __restrict__ nc_out,
                                                   int* __restrict__ counts,
                                                   float* __restrict__ out) {
    int b = blockIdx.y;
    int wave = (blockIdx.x * 256 + threadIdx.x) >> 6;
    int lane = threadIdx.x & 63;
    int sub = lane >> 4;
    int cb  = (lane & 15) << 2;
    const float* fbase = features + (size_t)b * NPTS * CCH;
    const float* crd = coords + (size_t)b * NPTS * 3;
    int* cnt = counts + (size_t)b * R3;
    float* obase = out + (size_t)b * CCH * R3;
    int p0 = wave * PPW;

    // 16KB feature tile, issued before everything else
    float4 f[16];
    #pragma unroll
    for (int i = 0; i < 16; ++i)
        f[i] = *(const float4*)(fbase + (size_t)(p0 + i * 4 + sub) * CCH + cb);

    // per-wave denom reduction from slotted partials (lane = slot)
    const float* ps = partials + ((size_t)b * SB + lane) * 3;
    float sx = ps[0], sy = ps[1], sz = ps[2];
    #pragma unroll
    for (int off = 1; off < 64; off <<= 1) {
        sx += __shfl_xor(sx, off);
        sy += __shfl_xor(sy, off);
        sz += __shfl_xor(sz, off);
    }
    float mx = fmaxf(fmaxf(sqrtf(sx), sqrtf(sy)), sqrtf(sz));
    float rd = 0.5f / mx;                      // 1/denom, denom = 2*mx

    // this lane's own point: nc + voxel id
    int pp = p0 + lane;
    float x = crd[pp * 3], y = crd[pp * 3 + 1], zz = crd[pp * 3 + 2];
    float m = (x + y + zz) * (1.0f / 3.0f);
    float fx = (x - m) * rd + 0.5f;
    float fy = (y - m) * rd + 0.5f;
    float fz = (zz - m) * rd + 0.5f;
    float tx = fminf(fmaxf(fx * (float)RR, 0.0f), (float)(RR - 1));
    float ty = fminf(fmaxf(fy * (float)RR, 0.0f), (float)(RR - 1));
    float tz = fminf(fmaxf(fz * (float)RR, 0.0f), (float)(RR - 1));
    float* onc = nc_out + (size_t)(b * NPTS + pp) * 3;
    onc[0] = tx; onc[1] = ty; onc[2] = tz;
    int v = (int)rintf(tx) * (RR * RR) + (int)rintf(ty) * RR + (int)rintf(tz);

    int v0 = __shfl(v, 0);
    if (__all(v == v0)) {
        if (lane == 0) atomicAdd(&cnt[v0], 64);
        float4 s = f[0];
        #pragma unroll
        for (int i = 1; i < 16; ++i) {
            s.x += f[i].x; s.y += f[i].y; s.z += f[i].z; s.w += f[i].w;
        }
        s.x += __shfl_xor(s.x, 16); s.x += __shfl_xor(s.x, 32);
        s.y += __shfl_xor(s.y, 16); s.y += __shfl_xor(s.y, 32);
        s.z += __shfl_xor(s.z, 16); s.z += __shfl_xor(s.z, 32);
        s.w += __shfl_xor(s.w, 16); s.w += __shfl_xor(s.w, 32);
        if (sub == 0) {
            size_t o = (size_t)cb * R3 + v0;
            atomicAdd(&obase[o],          s.x);
            atomicAdd(&obase[o + R3],     s.y);
            atomicAdd(&obase[o + 2 * R3], s.z);
            atomicAdd(&obase[o + 3 * R3], s.w);
        }
    } else {
        atomicAdd(&cnt[v], 1);
        #pragma unroll
        for (int i = 0; i < 16; ++i) {
            int vv = __shfl(v, i * 4 + sub);
            size_t o = (size_t)cb * R3 + vv;
            atomicAdd(&obase[o],          f[i].x);
            atomicAdd(&obase[o + R3],     f[i].y);
            atomicAdd(&obase[o + 2 * R3], f[i].z);
            atomicAdd(&obase[o + 3 * R3], f[i].w);
        }
    }
}

// ---------------- K3: divide hot voxels by their counts ----------------
__global__ __launch_bounds__(256) void scale_kernel(const int* __restrict__ counts,
                                                    float* __restrict__ out) {
    int t = blockIdx.x * 256 + threadIdx.x;        // 0 .. B*R3-1
    int lane = threadIdx.x & 63;
    int b = t >> 15;                               // R3 = 32768
    int vox = t & (R3 - 1);
    int cnt = counts[t];
    unsigned long long mask = __ballot(cnt > 1);
    while (mask) {
        int src = __ffsll(mask) - 1;
        mask &= mask - 1;
        int vv = __shfl(vox, src);
        int bb = __shfl(b, src);
        int cc = __shfl(cnt, src);
        float s = 1.0f / (float)cc;
        size_t o = ((size_t)bb * CCH + lane) * R3 + vv;
        out[o] *= s;
    }
}

extern "C" void kernel_launch(void* const* d_in, const int* in_sizes, int n_in,
                              void* d_out, int out_size, void* d_ws, size_t ws_size,
                              hipStream_t stream) {
    const float* features = (const float*)d_in[0];
    const float* coords   = (const float*)d_in[1];
    float* out = (float*)d_out;

    float* voxf = out;                                    // (B, C, R, R, R)
    float* nc   = out + (size_t)BATCH * CCH * R3;         // (B, N, 3)

    char* ws = (char*)d_ws;
    int*   counts   = (int*)ws;                           // B*R3 ints = 1 MiB
    float* partials = (float*)(ws + (1 << 20));           // SBT*3 floats = 6 KiB

    prep_kernel<<<SBT + VZB + CZB, 256, 0, stream>>>(coords, voxf, counts, partials);

    dim3 fgrid(FBLK, BATCH);
    feat_kernel<<<fgrid, 256, 0, stream>>>(features, coords, partials, nc, counts, voxf);

    scale_kernel<<<BATCH * R3 / 256, 256, 0, stream>>>(counts, voxf);
}